// Round 3
// baseline (349.750 us; speedup 1.0000x reference)
//
#include <hip/hip_runtime.h>
#include <math.h>

#define KNN   10
#define NPTS  8192
#define HID   64
#define NF    76

#define KEY_SENTINEL __longlong_as_double(0x7FE0000000000000LL)
#define F32_INF      __uint_as_float(0x7F800000u)

// ---------------------------------------------------------------------------
// Phase A: brute-force KNN, two-pass threshold scheme.
// Pass 1: per (query, chunk) keep 10 smallest d2 VALUES only (f32 bubble:
//         10x v_min_f32+v_max_f32 = 40 cyc vs 80 cyc for the old f64 keys).
//         Wave 0 merges the 8 chunk lists -> exact tau = 10th-smallest d2.
// Pass 2: rescan (identical d2 instruction sequence -> identical bits);
//         rare hits (d2 <= tau, j != n) append packed f64 keys
//         ((1<<62)|monotone_d2<<13|j) to per-query LDS lists.
// Phase 3: per query, f64-bubble the <=16 collected keys -> exact stable
//         (d2 asc, index asc) top-10 == jax.lax.top_k semantics.
// Block = 512 threads = 64 queries x 8 candidate chunks.
// ---------------------------------------------------------------------------
__global__ __launch_bounds__(512) void knn_kernel(const float* __restrict__ cloud,
                                                  int* __restrict__ knn_idx) {
    __shared__ float4 tile[512];              // 8 chunks x 64 candidates
    __shared__ float  pk[8][64][KNN];         // pass-1 partial value lists
    __shared__ double coll[64][16];           // pass-2 collected keys
    __shared__ float  tau[64];
    __shared__ int    cnt[64];

    const int t  = threadIdx.x;
    const int c  = t >> 6;                    // chunk 0..7 (== wave id)
    const int ql = t & 63;                    // query slot
    const int bx = blockIdx.x;                // 0..511
    const int b  = bx >> 7;                   // batch
    const int n0 = (bx & 127) * 64;
    const int n  = n0 + ql;                   // batch-local query index

    const float* cb = cloud + (size_t)b * NPTS * 3;
    const float qx = cb[n * 3 + 0];
    const float qy = cb[n * 3 + 1];
    const float qz = cb[n * 3 + 2];
    const float qs = fmaf(qz, qz, fmaf(qy, qy, qx * qx));

    const int chunk_base = c * (NPTS / 8);    // 1024 candidates per chunk

    // ---------------- pass 1: f32 top-10 values ----------------
    float bd[KNN];
#pragma unroll
    for (int s = 0; s < KNN; ++s) bd[s] = F32_INF;

    for (int i = 0; i < (NPTS / 8) / 64; ++i) {   // 16 tile iterations
        __syncthreads();
        const int cand = chunk_base + i * 64 + ql;
        const float x = cb[cand * 3 + 0];
        const float y = cb[cand * 3 + 1];
        const float z = cb[cand * 3 + 2];
        tile[t] = make_float4(x, y, z, fmaf(z, z, fmaf(y, y, x * x)));
        __syncthreads();

        const int jbase = chunk_base + i * 64;
        const int lbase = c * 64;
#pragma unroll 16
        for (int jj = 0; jj < 64; ++jj) {
            const float4 v = tile[lbase + jj];       // wave-uniform broadcast
            const int j = jbase + jj;
            const float dot = fmaf(v.z, qz, fmaf(v.y, qy, v.x * qx));
            float d2 = fmaf(-2.0f, dot, qs + v.w);
            d2 = (j == n) ? F32_INF : d2;            // self-exclusion
#pragma unroll
            for (int s = 0; s < KNN; ++s) {
                const float lo = fminf(bd[s], d2);
                d2 = fmaxf(bd[s], d2);
                bd[s] = lo;
            }
        }
    }

    __syncthreads();
#pragma unroll
    for (int s = 0; s < KNN; ++s) pk[c][ql][s] = bd[s];
    if (t < 64) cnt[t] = 0;
    __syncthreads();

    // wave 0: merge 8 chunk lists -> tau (exact 10th-smallest d2)
    if (t < 64) {
        float md[KNN];
#pragma unroll
        for (int s = 0; s < KNN; ++s) md[s] = F32_INF;
        for (int cc = 0; cc < 8; ++cc) {
#pragma unroll
            for (int s = 0; s < KNN; ++s) {
                float d = pk[cc][t][s];
#pragma unroll
                for (int u = 0; u < KNN; ++u) {
                    const float lo = fminf(md[u], d);
                    d = fmaxf(md[u], d);
                    md[u] = lo;
                }
            }
        }
        tau[t] = md[KNN - 1];
    }

    // ---------------- pass 2: collect hits ----------------
    for (int i = 0; i < (NPTS / 8) / 64; ++i) {
        __syncthreads();                          // 1st iter: tau visible
        const int cand = chunk_base + i * 64 + ql;
        const float x = cb[cand * 3 + 0];
        const float y = cb[cand * 3 + 1];
        const float z = cb[cand * 3 + 2];
        tile[t] = make_float4(x, y, z, fmaf(z, z, fmaf(y, y, x * x)));
        __syncthreads();

        const float tq = tau[ql];
        const int jbase = chunk_base + i * 64;
        const int lbase = c * 64;
#pragma unroll 16
        for (int jj = 0; jj < 64; ++jj) {
            const float4 v = tile[lbase + jj];
            const int j = jbase + jj;
            const float dot = fmaf(v.z, qz, fmaf(v.y, qy, v.x * qx));
            const float d2 = fmaf(-2.0f, dot, qs + v.w);
            if (d2 <= tq && j != n) {                // rare (~10/8192 per lane)
                const unsigned int fb = __float_as_uint(d2);
                const unsigned int m =
                    fb ^ ((unsigned int)((int)fb >> 31) | 0x80000000u);
                const unsigned long long kb =
                    (1ULL << 62) | ((unsigned long long)m << 13) | (unsigned long long)j;
                const int slot = atomicAdd(&cnt[ql], 1);
                if (slot < 16) coll[ql][slot] = __longlong_as_double((long long)kb);
            }
        }
    }

    __syncthreads();

    // ---------------- phase 3: exact stable top-10 ----------------
    if (t < 64) {
        const int m = min(cnt[t], 16);
        double md[KNN];
#pragma unroll
        for (int s = 0; s < KNN; ++s) md[s] = KEY_SENTINEL;
        for (int cc = 0; cc < 16; ++cc) {
            double key = (cc < m) ? coll[t][cc] : KEY_SENTINEL;
#pragma unroll
            for (int u = 0; u < KNN; ++u) {
                const double lo = fmin(md[u], key);
                key = fmax(md[u], key);
                md[u] = lo;
            }
        }
        int* outp = knn_idx + ((size_t)b * NPTS + (n0 + t)) * KNN;
#pragma unroll
        for (int s = 0; s < KNN; ++s)
            outp[s] = (int)((unsigned int)__double_as_longlong(md[s]) & 8191u);
    }
}

// ---------------------------------------------------------------------------
// Phase B: features + MLP (unchanged from R2 — fast enough for now).
// ---------------------------------------------------------------------------
__global__ __launch_bounds__(64) void feat_mlp_kernel(const float* __restrict__ cloud,
                                                      const float* __restrict__ W1,
                                                      const float* __restrict__ b1,
                                                      const float* __restrict__ W2,
                                                      const float* __restrict__ b2,
                                                      const int* __restrict__ knn_idx,
                                                      float* __restrict__ out) {
    __shared__ float w1s[NF * HID];
    __shared__ float b1s[HID];
    __shared__ float w2s[HID * 3];
    __shared__ float b2s[3];
    __shared__ float fs[64][NF + 1];          // +1 pad: stride 77 (odd)

    const int t = threadIdx.x;
    for (int idx = t; idx < NF * HID; idx += 64) w1s[idx] = W1[idx];
    b1s[t] = b1[t];
    for (int idx = t; idx < HID * 3; idx += 64) w2s[idx] = W2[idx];
    if (t < 3) b2s[t] = b2[t];

    const int gid = blockIdx.x * 64 + t;      // 0..32767
    const int b = gid >> 13;
    const int n = gid & (NPTS - 1);
    const float* cb = cloud + (size_t)b * NPTS * 3;

    const float cx = cb[n * 3 + 0];
    const float cy = cb[n * 3 + 1];
    const float cz = cb[n * 3 + 2];

    float nx[KNN], ny[KNN], nz[KNN];
    const int* ki = knn_idx + (size_t)gid * KNN;
#pragma unroll
    for (int k = 0; k < KNN; ++k) {
        const int j = ki[k];
        nx[k] = cb[j * 3 + 0];
        ny[k] = cb[j * 3 + 1];
        nz[k] = cb[j * 3 + 2];
    }

    float* fr = fs[t];
    fr[0] = cx; fr[1] = cy; fr[2] = cz;
#pragma unroll
    for (int k = 0; k < KNN; ++k) {
        fr[3 + 3 * k + 0] = nx[k];
        fr[3 + 3 * k + 1] = ny[k];
        fr[3 + 3 * k + 2] = nz[k];
    }
#pragma unroll
    for (int k = 0; k < KNN; ++k) {
        fr[33 + 3 * k + 0] = nx[k] - cx;
        fr[33 + 3 * k + 1] = ny[k] - cy;
        fr[33 + 3 * k + 2] = nz[k] - cz;
    }
#pragma unroll
    for (int k = 0; k < KNN; ++k) {
        const float rx = nx[k] - cx, ry = ny[k] - cy, rz = nz[k] - cz;
        fr[63 + k] = sqrtf(fmaf(rz, rz, fmaf(ry, ry, rx * rx)));
    }

    float mx = 0.f, my = 0.f, mz = 0.f;
#pragma unroll
    for (int k = 0; k < KNN; ++k) { mx += nx[k]; my += ny[k]; mz += nz[k]; }
    mx *= (1.0f / KNN); my *= (1.0f / KNN); mz *= (1.0f / KNN);
    float c00 = 0.f, c01 = 0.f, c02 = 0.f, c11 = 0.f, c12 = 0.f, c22 = 0.f;
#pragma unroll
    for (int k = 0; k < KNN; ++k) {
        const float ex = nx[k] - mx, ey = ny[k] - my, ez = nz[k] - mz;
        c00 = fmaf(ex, ex, c00); c01 = fmaf(ex, ey, c01); c02 = fmaf(ex, ez, c02);
        c11 = fmaf(ey, ey, c11); c12 = fmaf(ey, ez, c12); c22 = fmaf(ez, ez, c22);
    }
    const float sc = 1.0f / (KNN - 1);
    c00 *= sc; c01 *= sc; c02 *= sc; c11 *= sc; c12 *= sc; c22 *= sc;

    const double a00 = c00, a01 = c01, a02 = c02, a11 = c11, a12 = c12, a22 = c22;
    const double q = (a00 + a11 + a22) / 3.0;
    const double p1 = a01 * a01 + a02 * a02 + a12 * a12;
    const double d00 = a00 - q, d11 = a11 - q, d22 = a22 - q;
    const double p2 = d00 * d00 + d11 * d11 + d22 * d22 + 2.0 * p1;
    double l1, l2, l3;
    if (p2 < 1e-300) {
        l1 = l2 = l3 = q;
    } else {
        const double p = sqrt(p2 / 6.0);
        const double inv = 1.0 / p;
        const double e00 = d00 * inv, e11 = d11 * inv, e22 = d22 * inv;
        const double e01 = a01 * inv, e02 = a02 * inv, e12 = a12 * inv;
        double detB = e00 * (e11 * e22 - e12 * e12)
                    - e01 * (e01 * e22 - e12 * e02)
                    + e02 * (e01 * e12 - e11 * e02);
        double r = 0.5 * detB;
        r = fmin(1.0, fmax(-1.0, r));
        const double phi = acos(r) / 3.0;
        l1 = q + 2.0 * p * cos(phi);                          // largest
        l3 = q + 2.0 * p * cos(phi + 2.0943951023931953);     // smallest
        l2 = 3.0 * q - l1 - l3;
    }
    fr[73] = (float)((l1 - l2) / l1);
    fr[74] = (float)((l2 - l3) / l1);
    fr[75] = (float)(l3 / l1);

    __syncthreads();

    float h[HID];
#pragma unroll
    for (int j = 0; j < HID; ++j) h[j] = b1s[j];

#pragma unroll 4
    for (int f = 0; f < NF; ++f) {
        const float v = fr[f];
        const float4* w4 = reinterpret_cast<const float4*>(w1s + f * HID);
#pragma unroll
        for (int j4 = 0; j4 < HID / 4; ++j4) {
            const float4 w = w4[j4];
            h[4 * j4 + 0] = fmaf(v, w.x, h[4 * j4 + 0]);
            h[4 * j4 + 1] = fmaf(v, w.y, h[4 * j4 + 1]);
            h[4 * j4 + 2] = fmaf(v, w.z, h[4 * j4 + 2]);
            h[4 * j4 + 3] = fmaf(v, w.w, h[4 * j4 + 3]);
        }
    }

    float o0 = b2s[0], o1 = b2s[1], o2 = b2s[2];
#pragma unroll
    for (int j = 0; j < HID; ++j) {
        const float r = fmaxf(h[j], 0.0f);
        o0 = fmaf(r, w2s[j * 3 + 0], o0);
        o1 = fmaf(r, w2s[j * 3 + 1], o1);
        o2 = fmaf(r, w2s[j * 3 + 2], o2);
    }
    float* op = out + (size_t)gid * 3;
    op[0] = fmaxf(o0, 0.0f);
    op[1] = fmaxf(o1, 0.0f);
    op[2] = fmaxf(o2, 0.0f);
}

extern "C" void kernel_launch(void* const* d_in, const int* in_sizes, int n_in,
                              void* d_out, int out_size, void* d_ws, size_t ws_size,
                              hipStream_t stream) {
    const float* cloud = (const float*)d_in[0];   // [4,8192,3]
    const float* W1    = (const float*)d_in[1];   // [76,64]
    const float* b1    = (const float*)d_in[2];   // [64]
    const float* W2    = (const float*)d_in[3];   // [64,3]
    const float* b2    = (const float*)d_in[4];   // [3]
    float* out = (float*)d_out;                   // [4,8192,3]

    int* knn = (int*)d_ws;                        // 4*8192*10 ints = 1.25 MB

    knn_kernel<<<dim3(512), dim3(512), 0, stream>>>(cloud, knn);
    feat_mlp_kernel<<<dim3(512), dim3(64), 0, stream>>>(cloud, W1, b1, W2, b2, knn, out);
}

// Round 4
// 315.189 us; speedup vs baseline: 1.1097x; 1.1097x over previous
//
#include <hip/hip_runtime.h>
#include <math.h>

#define KNN    10
#define NPTS   8192
#define HID    64
#define NF     76
#define CHUNKS 16
#define CLEN   (NPTS / CHUNKS)   // 512
#define F32_INF __uint_as_float(0x7F800000u)

// ---------------------------------------------------------------------------
// Prep: pts4[i] = (x, y, z, x^2+y^2+z^2). Gives the KNN scan a 16B record it
// can fetch with one (scalar) load, and makes q.w/p.w bit-identical across
// passes/kernels.
// ---------------------------------------------------------------------------
__global__ __launch_bounds__(256) void prep_kernel(const float* __restrict__ cloud,
                                                   float4* __restrict__ pts4) {
    const int i = blockIdx.x * 256 + threadIdx.x;      // 0..32767
    const float x = cloud[i * 3 + 0];
    const float y = cloud[i * 3 + 1];
    const float z = cloud[i * 3 + 2];
    pts4[i] = make_float4(x, y, z, fmaf(z, z, fmaf(y, y, x * x)));
}

// ---------------------------------------------------------------------------
// KNN, two-pass, NO LDS in the scan loops. Candidate index is wave-uniform
// (readfirstlane) -> pts4[j] compiles to s_load; dist math feeds SGPR data
// into VALU (1 sgpr/op). Block = 1024 thr = 64 queries x 16 chunks of 512
// candidates; grid 512 -> 32 waves/CU nominal (LDS only ~50KB merge bufs).
// Pass 1: exact f32 top-10 VALUES per (query,chunk); wave0 merges -> tau.
// Pass 2: rescan (bit-identical d2), collect (d2<<13|j) keys for d2<=tau.
// Phase 3: u64-sort <=20 keys -> stable (d2 asc, idx asc) == jax top_k.
// ---------------------------------------------------------------------------
__global__ __launch_bounds__(1024) void knn_kernel(const float4* __restrict__ pts4,
                                                   unsigned short* __restrict__ knn_idx) {
    __shared__ float pk[CHUNKS][64][KNN];          // 40 KB
    __shared__ unsigned long long coll[64][20];    // 10 KB
    __shared__ float tau[64];
    __shared__ int   cnt[64];

    const int t  = threadIdx.x;
    const int c  = t >> 6;                    // chunk 0..15 (wave id)
    const int ql = t & 63;                    // query slot
    const int bx = blockIdx.x;                // 0..511
    const int b  = bx >> 7;                   // batch
    const int n0 = (bx & 127) * 64;
    const int n  = n0 + ql;                   // batch-local query index

    const float4* pb = pts4 + b * NPTS;
    const float4 q = pb[n];                   // divergent -> vector load
    const float qx = q.x, qy = q.y, qz = q.z, qs = q.w;

    const int cb0 = __builtin_amdgcn_readfirstlane(c * CLEN);

    // ---------------- pass 1: f32 top-10 values ----------------
    float bd[KNN];
#pragma unroll
    for (int s = 0; s < KNN; ++s) bd[s] = F32_INF;

#pragma unroll 8
    for (int i = 0; i < CLEN; ++i) {
        const float4 p = pb[cb0 + i];         // uniform -> s_load_dwordx4
        const float dot = fmaf(p.z, qz, fmaf(p.y, qy, p.x * qx));
        float d2 = fmaf(-2.0f, dot, qs + p.w);
        d2 = (cb0 + i == n) ? F32_INF : d2;   // self-exclusion
#pragma unroll
        for (int s = 0; s < KNN; ++s) {
            const float lo = fminf(bd[s], d2);
            d2 = fmaxf(bd[s], d2);
            bd[s] = lo;
        }
    }

#pragma unroll
    for (int s = 0; s < KNN; ++s) pk[c][ql][s] = bd[s];
    if (t < 64) cnt[t] = 0;
    __syncthreads();

    // wave 0: merge 16 chunk lists -> exact tau (10th smallest d2)
    if (t < 64) {
        float md[KNN];
#pragma unroll
        for (int s = 0; s < KNN; ++s) md[s] = F32_INF;
        for (int cc = 0; cc < CHUNKS; ++cc) {
#pragma unroll
            for (int s = 0; s < KNN; ++s) {
                float d = pk[cc][t][s];
#pragma unroll
                for (int u = 0; u < KNN; ++u) {
                    const float lo = fminf(md[u], d);
                    d = fmaxf(md[u], d);
                    md[u] = lo;
                }
            }
        }
        tau[t] = md[KNN - 1];
    }
    __syncthreads();

    // ---------------- pass 2: collect hits (rare) ----------------
    const float tq = tau[ql];
#pragma unroll 4
    for (int i = 0; i < CLEN; ++i) {
        const float4 p = pb[cb0 + i];
        const float dot = fmaf(p.z, qz, fmaf(p.y, qy, p.x * qx));
        const float d2 = fmaf(-2.0f, dot, qs + p.w);   // bit-identical to pass 1
        if (d2 <= tq && cb0 + i != n) {
            const unsigned int fb = __float_as_uint(d2);
            const unsigned int m =
                fb ^ ((unsigned int)((int)fb >> 31) | 0x80000000u);  // monotone map
            const unsigned long long key =
                ((unsigned long long)m << 13) | (unsigned long long)(cb0 + i);
            const int slot = atomicAdd(&cnt[ql], 1);
            if (slot < 20) coll[ql][slot] = key;
        }
    }
    __syncthreads();

    // ---------------- phase 3: exact stable top-10 ----------------
    if (t < 64) {
        const int m = min(cnt[t], 20);
        unsigned long long md[KNN];
#pragma unroll
        for (int s = 0; s < KNN; ++s) md[s] = ~0ULL;
        for (int cc = 0; cc < 20; ++cc) {
            unsigned long long key = (cc < m) ? coll[t][cc] : ~0ULL;
#pragma unroll
            for (int u = 0; u < KNN; ++u) {
                const bool lt = key < md[u];
                const unsigned long long lo = lt ? key : md[u];
                key = lt ? md[u] : key;
                md[u] = lo;
            }
        }
        unsigned short* outp = knn_idx + ((size_t)b * NPTS + (n0 + t)) * KNN;
#pragma unroll
        for (int s = 0; s < KNN; ++s)
            outp[s] = (unsigned short)(md[s] & 8191u);
    }
}

// ---------------------------------------------------------------------------
// Features + MLP, hidden dim split 2-way across lane pairs: thread = (point,
// sub), sub owns h[32]. 128-thr blocks (64 points), grid 512 -> 2x waves vs
// R3 and half the dependent-FMA chain depth. Layer-2 partials combined with
// one shfl_xor(1). Both subs duplicate the feature build (identical values,
// benign duplicate LDS writes, no divergence). w1s slice reads are 128B
// apart -> same banks, 2-way = free.
// ---------------------------------------------------------------------------
__global__ __launch_bounds__(128) void feat_mlp_kernel(const float4* __restrict__ pts4,
                                                       const float* __restrict__ W1,
                                                       const float* __restrict__ b1,
                                                       const float* __restrict__ W2,
                                                       const float* __restrict__ b2,
                                                       const unsigned short* __restrict__ knn_idx,
                                                       float* __restrict__ out) {
    __shared__ float w1s[NF * HID];
    __shared__ float b1s[HID];
    __shared__ float w2s[HID * 3];
    __shared__ float b2s[3];
    __shared__ float fs[64][NF + 1];          // stride 77 (odd) -> conflict-free

    const int t = threadIdx.x;
    for (int idx = t; idx < NF * HID; idx += 128) w1s[idx] = W1[idx];
    if (t < HID) b1s[t] = b1[t];
    for (int idx = t; idx < HID * 3; idx += 128) w2s[idx] = W2[idx];
    if (t < 3) b2s[t] = b2[t];

    const int pl  = t >> 1;                   // point slot 0..63
    const int sub = t & 1;                    // hidden-half owner
    const int gid = blockIdx.x * 64 + pl;     // 0..32767
    const int b = gid >> 13;
    const int n = gid & (NPTS - 1);
    const float4* pb = pts4 + b * NPTS;

    const float4 cq = pb[n];
    const float cx = cq.x, cy = cq.y, cz = cq.z;

    float nx[KNN], ny[KNN], nz[KNN];
    const unsigned short* ki = knn_idx + (size_t)gid * KNN;
#pragma unroll
    for (int k = 0; k < KNN; ++k) {
        const int j = ki[k];
        const float4 p = pb[j];
        nx[k] = p.x; ny[k] = p.y; nz[k] = p.z;
    }

    float* fr = fs[pl];
    fr[0] = cx; fr[1] = cy; fr[2] = cz;
#pragma unroll
    for (int k = 0; k < KNN; ++k) {
        fr[3 + 3 * k + 0] = nx[k];
        fr[3 + 3 * k + 1] = ny[k];
        fr[3 + 3 * k + 2] = nz[k];
    }
#pragma unroll
    for (int k = 0; k < KNN; ++k) {
        fr[33 + 3 * k + 0] = nx[k] - cx;
        fr[33 + 3 * k + 1] = ny[k] - cy;
        fr[33 + 3 * k + 2] = nz[k] - cz;
    }
#pragma unroll
    for (int k = 0; k < KNN; ++k) {
        const float rx = nx[k] - cx, ry = ny[k] - cy, rz = nz[k] - cz;
        fr[63 + k] = sqrtf(fmaf(rz, rz, fmaf(ry, ry, rx * rx)));
    }

    // covariance of neighbors (unbiased, /(K-1))
    float mx = 0.f, my = 0.f, mz = 0.f;
#pragma unroll
    for (int k = 0; k < KNN; ++k) { mx += nx[k]; my += ny[k]; mz += nz[k]; }
    mx *= (1.0f / KNN); my *= (1.0f / KNN); mz *= (1.0f / KNN);
    float c00 = 0.f, c01 = 0.f, c02 = 0.f, c11 = 0.f, c12 = 0.f, c22 = 0.f;
#pragma unroll
    for (int k = 0; k < KNN; ++k) {
        const float ex = nx[k] - mx, ey = ny[k] - my, ez = nz[k] - mz;
        c00 = fmaf(ex, ex, c00); c01 = fmaf(ex, ey, c01); c02 = fmaf(ex, ez, c02);
        c11 = fmaf(ey, ey, c11); c12 = fmaf(ey, ez, c12); c22 = fmaf(ez, ez, c22);
    }
    const float sc = 1.0f / (KNN - 1);
    c00 *= sc; c01 *= sc; c02 *= sc; c11 *= sc; c12 *= sc; c22 *= sc;

    // closed-form symmetric 3x3 eigenvalues (fp64 trig path)
    const double a00 = c00, a01 = c01, a02 = c02, a11 = c11, a12 = c12, a22 = c22;
    const double qd = (a00 + a11 + a22) / 3.0;
    const double p1 = a01 * a01 + a02 * a02 + a12 * a12;
    const double d00 = a00 - qd, d11 = a11 - qd, d22 = a22 - qd;
    const double p2 = d00 * d00 + d11 * d11 + d22 * d22 + 2.0 * p1;
    double l1, l2, l3;
    if (p2 < 1e-300) {
        l1 = l2 = l3 = qd;
    } else {
        const double p = sqrt(p2 / 6.0);
        const double inv = 1.0 / p;
        const double e00 = d00 * inv, e11 = d11 * inv, e22 = d22 * inv;
        const double e01 = a01 * inv, e02 = a02 * inv, e12 = a12 * inv;
        double detB = e00 * (e11 * e22 - e12 * e12)
                    - e01 * (e01 * e22 - e12 * e02)
                    + e02 * (e01 * e12 - e11 * e02);
        double r = 0.5 * detB;
        r = fmin(1.0, fmax(-1.0, r));
        const double phi = acos(r) / 3.0;
        l1 = qd + 2.0 * p * cos(phi);                          // largest
        l3 = qd + 2.0 * p * cos(phi + 2.0943951023931953);     // smallest
        l2 = 3.0 * qd - l1 - l3;
    }
    fr[73] = (float)((l1 - l2) / l1);
    fr[74] = (float)((l2 - l3) / l1);
    fr[75] = (float)(l3 / l1);

    __syncthreads();   // weights + features visible

    float h[HID / 2];
#pragma unroll
    for (int j = 0; j < HID / 2; ++j) h[j] = b1s[sub * 32 + j];

#pragma unroll 4
    for (int f = 0; f < NF; ++f) {
        const float v = fr[f];
        const float4* w4 = reinterpret_cast<const float4*>(w1s + f * HID + sub * 32);
#pragma unroll
        for (int j4 = 0; j4 < 8; ++j4) {
            const float4 w = w4[j4];
            h[4 * j4 + 0] = fmaf(v, w.x, h[4 * j4 + 0]);
            h[4 * j4 + 1] = fmaf(v, w.y, h[4 * j4 + 1]);
            h[4 * j4 + 2] = fmaf(v, w.z, h[4 * j4 + 2]);
            h[4 * j4 + 3] = fmaf(v, w.w, h[4 * j4 + 3]);
        }
    }

    float o0 = 0.f, o1 = 0.f, o2 = 0.f;
#pragma unroll
    for (int j = 0; j < HID / 2; ++j) {
        const float r = fmaxf(h[j], 0.0f);
        const int jj = sub * 32 + j;
        o0 = fmaf(r, w2s[jj * 3 + 0], o0);
        o1 = fmaf(r, w2s[jj * 3 + 1], o1);
        o2 = fmaf(r, w2s[jj * 3 + 2], o2);
    }
    o0 += __shfl_xor(o0, 1, 64);
    o1 += __shfl_xor(o1, 1, 64);
    o2 += __shfl_xor(o2, 1, 64);

    if (sub == 0) {
        float* op = out + (size_t)gid * 3;
        op[0] = fmaxf(o0 + b2s[0], 0.0f);
        op[1] = fmaxf(o1 + b2s[1], 0.0f);
        op[2] = fmaxf(o2 + b2s[2], 0.0f);
    }
}

extern "C" void kernel_launch(void* const* d_in, const int* in_sizes, int n_in,
                              void* d_out, int out_size, void* d_ws, size_t ws_size,
                              hipStream_t stream) {
    const float* cloud = (const float*)d_in[0];   // [4,8192,3]
    const float* W1    = (const float*)d_in[1];   // [76,64]
    const float* b1    = (const float*)d_in[2];   // [64]
    const float* W2    = (const float*)d_in[3];   // [64,3]
    const float* b2    = (const float*)d_in[4];   // [3]
    float* out = (float*)d_out;                   // [4,8192,3]

    float4* pts4 = (float4*)d_ws;                                   // 512 KB
    unsigned short* knn = (unsigned short*)((char*)d_ws + 4 * NPTS * 16);  // 640 KB

    prep_kernel<<<dim3(128), dim3(256), 0, stream>>>(cloud, pts4);
    knn_kernel<<<dim3(512), dim3(1024), 0, stream>>>(pts4, knn);
    feat_mlp_kernel<<<dim3(512), dim3(128), 0, stream>>>(pts4, W1, b1, W2, b2, knn, out);
}